// Round 2
// baseline (648.606 us; speedup 1.0000x reference)
//
#include <hip/hip_runtime.h>
#include <hip/hip_bf16.h>

typedef __attribute__((ext_vector_type(8))) short short8;   // 8 bf16 = one MFMA A/B frag
typedef __attribute__((ext_vector_type(4))) float f32x4;    // MFMA C/D frag

#define BLOCK 256      // 4 waves

// LDS W1^T layout: logical [n][k] bf16, row stride 256 B, byte offset
// XOR-swizzled by ((n&7)<<4) to break stride-256B bank conflicts on the
// ds_read_b128 fragment loads (guide §6 G4 / T2). Verified in round 1.
__device__ __forceinline__ int swz(int row, int k) {
    int byte = row * 256 + k * 2;
    return byte ^ ((row & 7) << 4);
}

__global__ __launch_bounds__(BLOCK, 4) void edge_mlp_kernel(
    const float* __restrict__ src,
    const float* __restrict__ dst,
    const int*   __restrict__ eli,   // [2,E]; width auto-detected (int32 or int64)
    const float* __restrict__ W1,    // [128,128] row-major
    const float* __restrict__ b1,    // [128]
    const float* __restrict__ W2,    // [128]
    const float* __restrict__ b2,    // [1]
    float* __restrict__ out,         // [E]
    int E)
{
    __shared__ __hip_bfloat16 ldsW[128 * 128]; // W1^T swizzled: [n][k], 32 KB
    __shared__ float ldsB1[128];
    __shared__ float ldsW2[128];
    __shared__ int   s_i64;

    const int tid  = threadIdx.x;
    const int lane = tid & 63;
    const int wave = tid >> 6;
    const int rr   = lane & 15;   // MFMA row/col-in-tile index
    const int kgrp = lane >> 4;   // 0..3

    // ---- one-time staging: W1^T (bf16, swizzled), b1, W2, index-width probe
    for (int idx = tid; idx < 128 * 128; idx += BLOCK) {
        int k = idx >> 7, n = idx & 127;           // coalesced read along n
        *(__hip_bfloat16*)((char*)ldsW + swz(n, k)) = __float2bfloat16(W1[idx]);
    }
    if (tid < 128) { ldsB1[tid] = b1[tid]; ldsW2[tid] = W2[tid]; }
    if (tid == 0) {
        // int64 little-endian => odd int32 words (upper halves) all zero.
        int any = 0;
        #pragma unroll
        for (int i = 0; i < 32; ++i) any |= eli[2 * i + 1];
        s_i64 = (any == 0) ? 1 : 0;
    }
    __syncthreads();   // the ONLY barrier — loop below is barrier-free

    const float bias2 = b2[0];
    const float4* src4 = (const float4*)src;
    const float4* dst4 = (const float4*)dst;
    const int i64 = s_i64;

    const int ngroups = (E + 15) >> 4;      // 16 edges per wave-group
    const int gw0 = blockIdx.x * 4 + wave;
    const int nw  = gridDim.x * 4;

    for (int g = gw0; g < ngroups; g += nw) {
        // this lane's edge row (4-way redundant across kgrp, coalesced)
        int e  = g * 16 + rr;
        int el = e < E ? e : E - 1;
        int r, c;
        if (i64) {
            const long long* e64 = (const long long*)eli;
            r = (int)e64[el]; c = (int)e64[E + el];
        } else {
            r = eli[el]; c = eli[E + el];
        }

        // ---- build A-fragments straight from global: lane owns
        // z[row=rr][k = kk*32 + kgrp*8 .. +7] = two float4s of src*dst.
        // 4 lanes sharing a row cover one 64B line per kk — coalesced.
        const float4* sp = src4 + (size_t)r * 32 + kgrp * 2;
        const float4* dp = dst4 + (size_t)c * 32 + kgrp * 2;
        short8 a[4];
        #pragma unroll
        for (int kk = 0; kk < 4; ++kk) {
            float4 s0 = sp[kk * 8];
            float4 s1 = sp[kk * 8 + 1];
            float4 d0 = dp[kk * 8];
            float4 d1 = dp[kk * 8 + 1];
            union { __hip_bfloat16 h[8]; short8 v; } af;
            af.h[0] = __float2bfloat16(s0.x * d0.x);
            af.h[1] = __float2bfloat16(s0.y * d0.y);
            af.h[2] = __float2bfloat16(s0.z * d0.z);
            af.h[3] = __float2bfloat16(s0.w * d0.w);
            af.h[4] = __float2bfloat16(s1.x * d1.x);
            af.h[5] = __float2bfloat16(s1.y * d1.y);
            af.h[6] = __float2bfloat16(s1.z * d1.z);
            af.h[7] = __float2bfloat16(s1.w * d1.w);
            a[kk] = af.v;
        }

        // ---- layer 1: 16 edges x 128 hidden, K=128
        f32x4 acc[8];
        #pragma unroll
        for (int t = 0; t < 8; ++t) acc[t] = (f32x4){0.f, 0.f, 0.f, 0.f};
        #pragma unroll
        for (int t = 0; t < 8; ++t) {
            #pragma unroll
            for (int kk = 0; kk < 4; ++kk) {
                short8 bf = *(const short8*)((const char*)ldsW +
                                             swz(t * 16 + rr, kk * 32 + kgrp * 8));
                acc[t] = __builtin_amdgcn_mfma_f32_16x16x32_bf16(a[kk], bf, acc[t], 0, 0, 0);
            }
        }

        // ---- epilogue: bias + relu + dot W2 (fp32), reduce over rr lanes
        float4 pv;
        #pragma unroll
        for (int rI = 0; rI < 4; ++rI) {
            float p = 0.f;
            #pragma unroll
            for (int t = 0; t < 8; ++t) {
                float h = acc[t][rI] + ldsB1[t * 16 + rr];   // col = t*16+rr
                h = fmaxf(h, 0.f);
                p = fmaf(h, ldsW2[t * 16 + rr], p);
            }
            p += __shfl_xor(p, 1, 64);
            p += __shfl_xor(p, 2, 64);
            p += __shfl_xor(p, 4, 64);
            p += __shfl_xor(p, 8, 64);
            ((float*)&pv)[rI] = p + bias2;                   // row = kgrp*4+rI
        }
        if (rr == 0) {
            int eo = g * 16 + kgrp * 4;
            if (eo + 3 < E) {
                *(float4*)(out + eo) = pv;                   // coalesced 64B/wave
            } else {
                #pragma unroll
                for (int rI = 0; rI < 4; ++rI)
                    if (eo + rI < E) out[eo + rI] = ((float*)&pv)[rI];
            }
        }
    }
}

extern "C" void kernel_launch(void* const* d_in, const int* in_sizes, int n_in,
                              void* d_out, int out_size, void* d_ws, size_t ws_size,
                              hipStream_t stream) {
    const float* src = (const float*)d_in[0];
    const float* dst = (const float*)d_in[1];
    const int*   eli = (const int*)d_in[2];
    const float* W1  = (const float*)d_in[3];
    const float* b1  = (const float*)d_in[4];
    const float* W2  = (const float*)d_in[5];
    const float* b2  = (const float*)d_in[6];
    float* out = (float*)d_out;

    const int E = in_sizes[2] / 2;   // flat count of [2,E]
    const int ngroups = (E + 15) >> 4;
    int nblocks = (ngroups + 3) / 4;
    int grid = nblocks < 2048 ? nblocks : 2048;

    edge_mlp_kernel<<<dim3(grid), dim3(BLOCK), 0, stream>>>(
        src, dst, eli, W1, b1, W2, b2, out, E);
}

// Round 3
// 247.744 us; speedup vs baseline: 2.6180x; 2.6180x over previous
//
#include <hip/hip_runtime.h>
#include <hip/hip_bf16.h>

typedef __attribute__((ext_vector_type(8))) short short8;   // 8 bf16 = one MFMA A/B frag
typedef __attribute__((ext_vector_type(4))) float f32x4;    // MFMA C/D frag

#define BLOCK 256      // 4 waves
#define TILE  64       // edges per block-tile

// Swizzled LDS byte address for logical [row][byteoff] with 256-B rows.
// XOR ((row&7)<<4) breaks bank conflicts on b128 fragment reads (verified r1/r2).
__device__ __forceinline__ int swzB(int row, int boff) {
    return (row << 8) + (boff ^ ((row & 7) << 4));
}

// ---------------- pre-pass: f32 -> bf16 tables in workspace ----------------
__global__ __launch_bounds__(256) void cvt_bf16_kernel(
    const float* __restrict__ a, const float* __restrict__ b,
    __hip_bfloat16* __restrict__ oa, __hip_bfloat16* __restrict__ ob, int n)
{
    const int i = blockIdx.x * blockDim.x + threadIdx.x;
    const int stride = gridDim.x * blockDim.x;
    const float4* a4 = (const float4*)a;
    const float4* b4 = (const float4*)b;
    const int n8 = n >> 3;
    for (int j = i; j < n8; j += stride) {
        float4 x0 = a4[2 * j], x1 = a4[2 * j + 1];
        float4 y0 = b4[2 * j], y1 = b4[2 * j + 1];
        union { __hip_bfloat16 h[8]; uint4 u; } pa, pb;
        pa.h[0]=__float2bfloat16(x0.x); pa.h[1]=__float2bfloat16(x0.y);
        pa.h[2]=__float2bfloat16(x0.z); pa.h[3]=__float2bfloat16(x0.w);
        pa.h[4]=__float2bfloat16(x1.x); pa.h[5]=__float2bfloat16(x1.y);
        pa.h[6]=__float2bfloat16(x1.z); pa.h[7]=__float2bfloat16(x1.w);
        pb.h[0]=__float2bfloat16(y0.x); pb.h[1]=__float2bfloat16(y0.y);
        pb.h[2]=__float2bfloat16(y0.z); pb.h[3]=__float2bfloat16(y0.w);
        pb.h[4]=__float2bfloat16(y1.x); pb.h[5]=__float2bfloat16(y1.y);
        pb.h[6]=__float2bfloat16(y1.z); pb.h[7]=__float2bfloat16(y1.w);
        ((uint4*)oa)[j] = pa.u;
        ((uint4*)ob)[j] = pb.u;
    }
    for (int j = (n8 << 3) + i; j < n; j += stride) {   // tail (n%8)
        oa[j] = __float2bfloat16(a[j]);
        ob[j] = __float2bfloat16(b[j]);
    }
}

// ---------------- fused edge-MLP ----------------
// Per block: 4 waves; wave w owns hidden cols [w*32, w*32+32) with W1^T frags
// IN REGISTERS. Per 64-edge tile: cooperative full-row gather (4 rows x 256B
// contiguous per wave-instr) -> bf16 z into swizzled LDS dbuf -> each wave
// MFMAs all 64 edges x its 32 cols -> relu+W2 partial -> pbuf -> wave0 sums.
template<bool BF16G>
__global__ __launch_bounds__(BLOCK, 3) void edge_mlp_kernel(
    const float* __restrict__ srcf, const float* __restrict__ dstf,
    const __hip_bfloat16* __restrict__ srcb, const __hip_bfloat16* __restrict__ dstb,
    const int*   __restrict__ eli,
    const float* __restrict__ W1, const float* __restrict__ b1,
    const float* __restrict__ W2, const float* __restrict__ b2,
    float* __restrict__ out, int E)
{
    // region overlay: prologue = W1^T staging (32 KB); loop = Z dbuf 2x16 KB
    __shared__ __align__(16) char ldsA[32768];
    __shared__ __align__(16) float pbuf[4][TILE];
    __shared__ int s_i64;

    const int tid  = threadIdx.x;
    const int lane = tid & 63;
    const int w    = tid >> 6;
    const int rr   = lane & 15;
    const int kgrp = lane >> 4;
    const int ch   = tid & 15;       // 16-B chunk within a 256-B bf16 row
    const int mrow = tid >> 4;       // 0..15: row-within-pass

    // ---- prologue: stage W1^T (bf16, swizzled) + index-width probe
    for (int idx = tid; idx < 128 * 128; idx += BLOCK) {
        int k = idx >> 7, n = idx & 127;
        *(__hip_bfloat16*)(ldsA + swzB(n, k * 2)) = __float2bfloat16(W1[idx]);
    }
    if (tid == 0) {
        int any = 0;
        #pragma unroll
        for (int i = 0; i < 32; ++i) any |= eli[2 * i + 1];
        s_i64 = (any == 0) ? 1 : 0;
    }
    __syncthreads();

    // B-frags (this wave's 32 hidden cols) -> registers, then free the region
    short8 bfr[2][4];
    #pragma unroll
    for (int t = 0; t < 2; ++t)
        #pragma unroll
        for (int kk = 0; kk < 4; ++kk)
            bfr[t][kk] = *(const short8*)(ldsA + swzB(w * 32 + t * 16 + rr,
                                                      kk * 64 + kgrp * 16));
    float b1s[2], w2s[2];
    #pragma unroll
    for (int t = 0; t < 2; ++t) {
        b1s[t] = b1[w * 32 + t * 16 + rr];
        w2s[t] = W2[w * 32 + t * 16 + rr];
    }
    const float bias2 = b2[0];
    const int i64f = s_i64;

    const int ntiles = (E + TILE - 1) / TILE;
    const int grid = gridDim.x;
    const int bid  = blockIdx.x;
    const int nit  = (bid < ntiles) ? ((ntiles - 1 - bid) / grid + 1) : 0;

    int ri[4], ci[4];        // prefetched indices (tile +2)
    short8 sv[4], dv[4];     // staged bf16 rows (tile +1)
    float4 svf[8], dvf[8];   // f32 fallback staging

    // index loader for tile tg (clamped)
    auto loadIdx = [&](int tg, int* r4, int* c4) {
        tg = tg < ntiles ? tg : ntiles - 1;
        #pragma unroll
        for (int p = 0; p < 4; ++p) {
            int e = tg * TILE + p * 16 + mrow;
            e = e < E ? e : E - 1;
            if (i64f) {
                const long long* e64 = (const long long*)eli;
                r4[p] = (int)e64[e]; c4[p] = (int)e64[(size_t)E + e];
            } else {
                r4[p] = eli[e]; c4[p] = eli[(size_t)E + e];
            }
        }
    };
    auto loadRows = [&](const int* r4, const int* c4) {
        if constexpr (BF16G) {
            const short8* s8 = (const short8*)srcb;
            const short8* d8 = (const short8*)dstb;
            #pragma unroll
            for (int p = 0; p < 4; ++p) {
                sv[p] = s8[(size_t)r4[p] * 16 + ch];
                dv[p] = d8[(size_t)c4[p] * 16 + ch];
            }
        } else {
            const float4* s4 = (const float4*)srcf;
            const float4* d4 = (const float4*)dstf;
            #pragma unroll
            for (int p = 0; p < 4; ++p) {
                svf[p * 2]     = s4[(size_t)r4[p] * 32 + ch];
                svf[p * 2 + 1] = s4[(size_t)r4[p] * 32 + 16 + ch];
                dvf[p * 2]     = d4[(size_t)c4[p] * 32 + ch];
                dvf[p * 2 + 1] = d4[(size_t)c4[p] * 32 + 16 + ch];
            }
        }
    };
    auto writeZ = [&](int buf) {
        char* zb = ldsA + (buf << 14);
        if constexpr (BF16G) {
            #pragma unroll
            for (int p = 0; p < 4; ++p) {
                int m = p * 16 + mrow;
                union { __hip_bfloat16 h[8]; short8 v; } pr;
                #pragma unroll
                for (int j = 0; j < 8; ++j) {
                    float fs = __bfloat162float(((const __hip_bfloat16*)&sv[p])[j]);
                    float fd = __bfloat162float(((const __hip_bfloat16*)&dv[p])[j]);
                    pr.h[j] = __float2bfloat16(fs * fd);
                }
                *(short8*)(zb + swzB(m, ch * 16)) = pr.v;
            }
        } else {
            #pragma unroll
            for (int p = 0; p < 4; ++p) {
                int m = p * 16 + mrow;
                union { __hip_bfloat16 h[4]; uint2 u; } q0, q1;
                float4 a0 = svf[p*2], b0 = dvf[p*2], a1 = svf[p*2+1], b1v = dvf[p*2+1];
                q0.h[0]=__float2bfloat16(a0.x*b0.x); q0.h[1]=__float2bfloat16(a0.y*b0.y);
                q0.h[2]=__float2bfloat16(a0.z*b0.z); q0.h[3]=__float2bfloat16(a0.w*b0.w);
                q1.h[0]=__float2bfloat16(a1.x*b1v.x); q1.h[1]=__float2bfloat16(a1.y*b1v.y);
                q1.h[2]=__float2bfloat16(a1.z*b1v.z); q1.h[3]=__float2bfloat16(a1.w*b1v.w);
                *(uint2*)(zb + swzB(m, ch * 8))       = q0.u;
                *(uint2*)(zb + swzB(m, 128 + ch * 8)) = q1.u;
            }
        }
    };

    // ---- pipeline prologue
    {
        int r0[4], c0[4];
        loadIdx(bid, r0, c0);
        loadRows(r0, c0);            // tile0 rows -> regs
        loadIdx(bid + grid, ri, ci); // tile1 idx
        __syncthreads();             // all W-frag LDS reads done -> overlay OK
        writeZ(0);                   // tile0 -> Z[0]
        loadRows(ri, ci);            // tile1 rows
        loadIdx(bid + 2 * grid, ri, ci); // tile2 idx
        __syncthreads();             // Z[0] ready
    }

    int cur = 0;
    for (int it = 0; it < nit; ++it) {
        const int tg = bid + it * grid;
        char* zb = ldsA + (cur << 14);

        // ---- compute: 64 edges x this wave's 32 hidden cols
        f32x4 acc[4][2];
        #pragma unroll
        for (int i = 0; i < 4; ++i)
            #pragma unroll
            for (int t = 0; t < 2; ++t)
                acc[i][t] = (f32x4){0.f, 0.f, 0.f, 0.f};
        #pragma unroll
        for (int ip = 0; ip < 2; ++ip) {
            short8 af[2][4];
            #pragma unroll
            for (int ii = 0; ii < 2; ++ii)
                #pragma unroll
                for (int kk = 0; kk < 4; ++kk)
                    af[ii][kk] = *(const short8*)(zb + swzB((ip*2+ii)*16 + rr,
                                                            kk*64 + kgrp*16));
            #pragma unroll
            for (int kk = 0; kk < 4; ++kk)
                #pragma unroll
                for (int ii = 0; ii < 2; ++ii)
                    #pragma unroll
                    for (int t = 0; t < 2; ++t)
                        acc[ip*2+ii][t] = __builtin_amdgcn_mfma_f32_16x16x32_bf16(
                            af[ii][kk], bfr[t][kk], acc[ip*2+ii][t], 0, 0, 0);
        }

        // ---- epilogue: relu + W2-dot partial over this wave's 32 cols
        #pragma unroll
        for (int i = 0; i < 4; ++i) {
            float4 p4;
            #pragma unroll
            for (int rI = 0; rI < 4; ++rI) {
                float p = 0.f;
                #pragma unroll
                for (int t = 0; t < 2; ++t) {
                    float h = acc[i][t][rI] + b1s[t];
                    h = fmaxf(h, 0.f);
                    p = fmaf(h, w2s[t], p);
                }
                p += __shfl_xor(p, 1, 64);
                p += __shfl_xor(p, 2, 64);
                p += __shfl_xor(p, 4, 64);
                p += __shfl_xor(p, 8, 64);
                ((float*)&p4)[rI] = p;
            }
            if (rr == 0)
                *(float4*)&pbuf[w][i * 16 + kgrp * 4] = p4;
        }
        __syncthreads();             // B1: pbuf complete, Z[cur] consumed

        writeZ(cur ^ 1);             // stage tile it+1 (regs -> LDS)
        loadRows(ri, ci);            // issue rows for tile it+2
        loadIdx(bid + (it + 3) * grid, ri, ci);  // idx tile it+3

        if (w == 0) {                // combine partials, store tile tg
            int e = tg * TILE + lane;
            float q = pbuf[0][lane] + pbuf[1][lane] + pbuf[2][lane] + pbuf[3][lane];
            if (e < E) out[e] = q + bias2;
        }
        __syncthreads();             // B2: Z[cur^1] ready
        cur ^= 1;
    }
}

extern "C" void kernel_launch(void* const* d_in, const int* in_sizes, int n_in,
                              void* d_out, int out_size, void* d_ws, size_t ws_size,
                              hipStream_t stream) {
    const float* src = (const float*)d_in[0];
    const float* dst = (const float*)d_in[1];
    const int*   eli = (const int*)d_in[2];
    const float* W1  = (const float*)d_in[3];
    const float* b1  = (const float*)d_in[4];
    const float* W2  = (const float*)d_in[5];
    const float* b2  = (const float*)d_in[6];
    float* out = (float*)d_out;

    const int E = in_sizes[2] / 2;
    const int nsrc = in_sizes[0];            // N_NODES * D floats
    const size_t need = (size_t)(in_sizes[0] + in_sizes[1]) * sizeof(__hip_bfloat16);
    const int ntiles = (E + TILE - 1) / TILE;
    int grid = ntiles < 1024 ? ntiles : 1024;

    if (ws_size >= need) {
        __hip_bfloat16* srcb = (__hip_bfloat16*)d_ws;
        __hip_bfloat16* dstb = srcb + nsrc;
        cvt_bf16_kernel<<<dim3(2048), dim3(256), 0, stream>>>(src, dst, srcb, dstb, nsrc);
        edge_mlp_kernel<true><<<dim3(grid), dim3(BLOCK), 0, stream>>>(
            src, dst, srcb, dstb, eli, W1, b1, W2, b2, out, E);
    } else {
        edge_mlp_kernel<false><<<dim3(grid), dim3(BLOCK), 0, stream>>>(
            src, dst, (const __hip_bfloat16*)nullptr, (const __hip_bfloat16*)nullptr,
            eli, W1, b1, W2, b2, out, E);
    }
}

// Round 4
// 169.047 us; speedup vs baseline: 3.8368x; 1.4655x over previous
//
#include <hip/hip_runtime.h>
#include <hip/hip_bf16.h>

typedef __attribute__((ext_vector_type(8))) short short8;    // 8 bf16 = 32x32x16 A/B frag
typedef __attribute__((ext_vector_type(16))) float f32x16;   // 32x32 C/D frag

#define BLOCK 256      // 4 waves
#define GTILE 32       // edges per wave-group (one 32x32 MFMA M-tile)

// Swizzled LDS byte address for logical [row][boff] with 256-B rows.
// XOR ((row&15)<<4): 16-row period over 16 slots -> every b128 access
// pattern in this kernel is bank-uniform (8 dwords/bank = baseline).
__device__ __forceinline__ int swz16(int row, int boff) {
    return (row << 8) + (boff ^ ((row & 15) << 4));
}

// ---------------- pre-pass: f32 -> bf16 tables in workspace ----------------
__global__ __launch_bounds__(256) void cvt_bf16_kernel(
    const float* __restrict__ a, const float* __restrict__ b,
    __hip_bfloat16* __restrict__ oa, __hip_bfloat16* __restrict__ ob, int n)
{
    const int i = blockIdx.x * blockDim.x + threadIdx.x;
    const int stride = gridDim.x * blockDim.x;
    const float4* a4 = (const float4*)a;
    const float4* b4 = (const float4*)b;
    const int n8 = n >> 3;
    for (int j = i; j < n8; j += stride) {
        float4 x0 = a4[2 * j], x1 = a4[2 * j + 1];
        float4 y0 = b4[2 * j], y1 = b4[2 * j + 1];
        union { __hip_bfloat16 h[8]; uint4 u; } pa, pb;
        pa.h[0]=__float2bfloat16(x0.x); pa.h[1]=__float2bfloat16(x0.y);
        pa.h[2]=__float2bfloat16(x0.z); pa.h[3]=__float2bfloat16(x0.w);
        pa.h[4]=__float2bfloat16(x1.x); pa.h[5]=__float2bfloat16(x1.y);
        pa.h[6]=__float2bfloat16(x1.z); pa.h[7]=__float2bfloat16(x1.w);
        pb.h[0]=__float2bfloat16(y0.x); pb.h[1]=__float2bfloat16(y0.y);
        pb.h[2]=__float2bfloat16(y0.z); pb.h[3]=__float2bfloat16(y0.w);
        pb.h[4]=__float2bfloat16(y1.x); pb.h[5]=__float2bfloat16(y1.y);
        pb.h[6]=__float2bfloat16(y1.z); pb.h[7]=__float2bfloat16(y1.w);
        ((uint4*)oa)[j] = pa.u;
        ((uint4*)ob)[j] = pb.u;
    }
    for (int j = (n8 << 3) + i; j < n; j += stride) {
        oa[j] = __float2bfloat16(a[j]);
        ob[j] = __float2bfloat16(b[j]);
    }
}

// ---------------- fused edge-MLP, barrier-free waves ----------------
// Per block: 4 independent waves. W1^T in shared LDS (32 KB, read-only after
// one barrier). Each wave: private 8 KB Z buffer, 32 edges/tile, 32x32x16
// MFMA over full 128 hidden, register-prefetched gather 1 tile ahead.
template<bool BF16G>
__global__ __launch_bounds__(BLOCK, 2) void edge_mlp_kernel(
    const float* __restrict__ srcf, const float* __restrict__ dstf,
    const __hip_bfloat16* __restrict__ srcb, const __hip_bfloat16* __restrict__ dstb,
    const int*   __restrict__ eli,
    const float* __restrict__ W1, const float* __restrict__ b1,
    const float* __restrict__ W2, const float* __restrict__ b2,
    float* __restrict__ out, int E)
{
    __shared__ __align__(16) char lds[65536];   // [0,32K)=W1^T, [32K,64K)=4x8K Z
    __shared__ int s_i64;

    const int tid  = threadIdx.x;
    const int lane = tid & 63;
    const int w    = tid >> 6;
    const int n32  = lane & 31;   // MFMA row/col-in-tile
    const int half = lane >> 5;   // k-half selector
    const int ch   = lane & 15;   // 16-B chunk within a 256-B row
    const int rq   = lane >> 4;   // 0..3: row-within-quad

    // ---- prologue: stage W1^T (bf16, swizzled) + index-width probe
    for (int idx = tid; idx < 128 * 128; idx += BLOCK) {
        int k = idx >> 7, n = idx & 127;                 // coalesced along n
        *(__hip_bfloat16*)(lds + swz16(n, k * 2)) = __float2bfloat16(W1[idx]);
    }
    if (tid == 0) {
        int any = 0;
        #pragma unroll
        for (int i = 0; i < 32; ++i) any |= eli[2 * i + 1];
        s_i64 = (any == 0) ? 1 : 0;
    }
    __syncthreads();   // the ONLY barrier

    char* zb = lds + 32768 + (w << 13);   // this wave's private 8 KB

    float b1s[4], w2s[4];
    #pragma unroll
    for (int cb = 0; cb < 4; ++cb) {
        b1s[cb] = b1[cb * 32 + n32];
        w2s[cb] = W2[cb * 32 + n32];
    }
    const float bias2 = b2[0];
    const int i64f = s_i64;

    const int ngroups = (E + GTILE - 1) / GTILE;
    const int step = gridDim.x * 4;
    int g = blockIdx.x * 4 + w;
    if (g >= ngroups) return;   // safe: no barriers after this point

    // lane-parallel index vector: lanes 0-31 = src idx, 32-63 = dst idx
    auto idxload = [&](int gg) -> int {
        gg = gg < ngroups ? gg : ngroups - 1;
        int e = gg * GTILE + n32; if (e >= E) e = E - 1;
        size_t off = half ? (size_t)E + (size_t)e : (size_t)e;
        return i64f ? eli[2 * off] : eli[off];   // low dword of int64 is the value
    };

    short8 sv[8], dv[8];   // prefetched bf16 rows (next tile), 64 VGPR
    auto loadRows = [&](int iv) {
        const short8* s8 = (const short8*)srcb;
        const short8* d8 = (const short8*)dstb;
        #pragma unroll
        for (int i = 0; i < 8; ++i) {
            int R = i * 4 + rq;                  // per instr: 4 rows x 256B contiguous
            int r = __shfl(iv, R, 64);
            int c = __shfl(iv, 32 + R, 64);
            sv[i] = s8[(size_t)r * 16 + ch];
            dv[i] = d8[(size_t)c * 16 + ch];
        }
    };

    int iv_cur = idxload(g);
    if constexpr (BF16G) loadRows(iv_cur);
    int iv_nxt = idxload(g + step);

    for (; g < ngroups; g += step) {
        asm volatile("" ::: "memory");   // compiler fence across loop back-edge
                                         // (Z buffer reuse: stores vs prior loads)
        // ---- stage current tile's Z (product, bf16, swizzled) into zb
        if constexpr (BF16G) {
            #pragma unroll
            for (int i = 0; i < 8; ++i) {
                int R = i * 4 + rq;
                union { __hip_bfloat16 h[8]; short8 v; } pr;
                #pragma unroll
                for (int j = 0; j < 8; ++j) {
                    float fs = __bfloat162float(((const __hip_bfloat16*)&sv[i])[j]);
                    float fd = __bfloat162float(((const __hip_bfloat16*)&dv[i])[j]);
                    pr.h[j] = __float2bfloat16(fs * fd);
                }
                *(short8*)(zb + swz16(R, ch * 16)) = pr.v;
            }
            // T14: issue next tile's gather now; latency hides under MFMA+epilogue
            int iv2 = idxload(g + 2 * step);
            loadRows(iv_nxt);
            iv_nxt = iv2;
        } else {
            const float4* s4 = (const float4*)srcf;
            const float4* d4 = (const float4*)dstf;
            #pragma unroll
            for (int i = 0; i < 8; ++i) {
                int R = i * 4 + rq;
                int r = __shfl(iv_cur, R, 64);
                int c = __shfl(iv_cur, 32 + R, 64);
                float4 a0 = s4[(size_t)r * 32 + ch * 2];
                float4 a1 = s4[(size_t)r * 32 + ch * 2 + 1];
                float4 c0 = d4[(size_t)c * 32 + ch * 2];
                float4 c1 = d4[(size_t)c * 32 + ch * 2 + 1];
                union { __hip_bfloat16 h[8]; short8 v; } pr;
                pr.h[0] = __float2bfloat16(a0.x * c0.x);
                pr.h[1] = __float2bfloat16(a0.y * c0.y);
                pr.h[2] = __float2bfloat16(a0.z * c0.z);
                pr.h[3] = __float2bfloat16(a0.w * c0.w);
                pr.h[4] = __float2bfloat16(a1.x * c1.x);
                pr.h[5] = __float2bfloat16(a1.y * c1.y);
                pr.h[6] = __float2bfloat16(a1.z * c1.z);
                pr.h[7] = __float2bfloat16(a1.w * c1.w);
                *(short8*)(zb + swz16(R, ch * 16)) = pr.v;
            }
            iv_cur = iv_nxt;
            iv_nxt = idxload(g + 2 * step);
        }

        // ---- layer 1: 32 edges x 128 hidden, K=128 (8 x K16 steps)
        f32x16 acc[4];
        #pragma unroll
        for (int cb = 0; cb < 4; ++cb)
            #pragma unroll
            for (int j = 0; j < 16; ++j)
                acc[cb][j] = 0.f;

        __builtin_amdgcn_s_setprio(1);
        #pragma unroll
        for (int kk = 0; kk < 8; ++kk) {
            // A: row=lane&31, k = kk*16 + half*8 + j
            short8 af = *(const short8*)(zb + swz16(n32, kk * 32 + half * 16));
            #pragma unroll
            for (int cb = 0; cb < 4; ++cb) {
                short8 bf = *(const short8*)(lds + swz16(cb * 32 + n32,
                                                         kk * 32 + half * 16));
                acc[cb] = __builtin_amdgcn_mfma_f32_32x32x16_bf16(af, bf, acc[cb], 0, 0, 0);
            }
        }
        __builtin_amdgcn_s_setprio(0);

        // ---- epilogue: relu + W2-dot; transpose partials through zb (Z consumed)
        // lane holds hidden col n32 (per cb); D row = (r&3)+8*(r>>2)+4*half.
        #pragma unroll
        for (int r = 0; r < 16; ++r) {
            float p = 0.f;
            #pragma unroll
            for (int cb = 0; cb < 4; ++cb) {
                float h = acc[cb][r] + b1s[cb];
                h = fmaxf(h, 0.f);
                p = fmaf(h, w2s[cb], p);
            }
            int R = (r & 3) + 8 * (r >> 2) + 4 * half;
            // partial-row layout: 128 B/edge-row, XOR'd so reads are conflict-free
            *(float*)(zb + ((R << 7) + ((n32 << 2) ^ ((R & 7) << 4)))) = p;
        }
        asm volatile("" ::: "memory");
        float tot = 0.f;
        #pragma unroll
        for (int j = 0; j < 4; ++j) {
            float4 v = *(const float4*)(zb + ((n32 << 7) +
                         ((half * 64 + j * 16) ^ ((n32 & 7) << 4))));
            tot += v.x + v.y + v.z + v.w;
        }
        tot += __shfl_xor(tot, 32, 64);   // combine the two 16-partial halves
        int e = g * GTILE + n32;
        if (half == 0 && e < E)
            __builtin_nontemporal_store(tot + bias2, &out[e]);
    }
}

extern "C" void kernel_launch(void* const* d_in, const int* in_sizes, int n_in,
                              void* d_out, int out_size, void* d_ws, size_t ws_size,
                              hipStream_t stream) {
    const float* src = (const float*)d_in[0];
    const float* dst = (const float*)d_in[1];
    const int*   eli = (const int*)d_in[2];
    const float* W1  = (const float*)d_in[3];
    const float* b1  = (const float*)d_in[4];
    const float* W2  = (const float*)d_in[5];
    const float* b2  = (const float*)d_in[6];
    float* out = (float*)d_out;

    const int E = in_sizes[2] / 2;
    const int nsrc = in_sizes[0];
    const size_t need = (size_t)(in_sizes[0] + in_sizes[1]) * sizeof(__hip_bfloat16);
    const int ngroups = (E + GTILE - 1) / GTILE;
    int nblocks = (ngroups + 3) / 4;
    int grid = nblocks < 512 ? nblocks : 512;   // 2 blocks/CU resident, grid-stride

    if (ws_size >= need) {
        __hip_bfloat16* srcb = (__hip_bfloat16*)d_ws;
        __hip_bfloat16* dstb = srcb + nsrc;
        cvt_bf16_kernel<<<dim3(2048), dim3(256), 0, stream>>>(src, dst, srcb, dstb, nsrc);
        edge_mlp_kernel<true><<<dim3(grid), dim3(BLOCK), 0, stream>>>(
            src, dst, srcb, dstb, eli, W1, b1, W2, b2, out, E);
    } else {
        edge_mlp_kernel<false><<<dim3(grid), dim3(BLOCK), 0, stream>>>(
            src, dst, (const __hip_bfloat16*)nullptr, (const __hip_bfloat16*)nullptr,
            eli, W1, b1, W2, b2, out, E);
    }
}